// Round 11
// baseline (56.364 us; speedup 1.0000x reference)
//
#include <hip/hip_runtime.h>
#include <hip/hip_cooperative_groups.h>
#include <math.h>

#define SRf 48000.0f
#define CSOUND 343.0f
#define RIR_LEN 24000
#define TAPS 81
#define HALFT 40
#define NB 8
#define NM 21                 // per-axis entries with order <= 10
#define NTRIP (NM * NM * NM)  // 9261 candidate triples
#define NSL 16                // image-slices per batch -> 128 co-resident blocks
#define BLOCK 1024
#define CAPS 256              // per-slice keeper capacity (mean ~98)
#define SPAN (RIR_LEN / NSL)  // 1500 samples reduced per block

namespace cg = cooperative_groups;

// 0.9^q for q = 0..10
__device__ __constant__ float c_beta[11] = {
    1.0f, 0.9f, 0.81f, 0.729f, 0.6561f, 0.59049f, 0.531441f,
    0.4782969f, 0.43046721f, 0.387420489f, 0.3486784401f};

// Per-axis image table restricted to order <= 10 (pure arithmetic):
//   m in [0,10]:  p=0, n=m-5  -> sign=+1, off=2n, order=2|n|
//   m in [11,20]: p=1, n=m-15 -> sign=-1, off=2n, order=|n-1|+|n|
__device__ __forceinline__ void axis_entry(int m, float& sgn, float& off, int& ord) {
    if (m < 11) {
        int n = m - 5;
        sgn = 1.0f;
        off = 2.0f * (float)n;
        ord = 2 * abs(n);
    } else {
        int n = m - 15;
        sgn = -1.0f;
        off = 2.0f * (float)n;
        ord = abs(n - 1) + abs(n);
    }
}

// Single cooperative kernel: paint partials -> grid.sync() -> reduce.
// 128 blocks x 1024 thr, 96KB LDS -> 1 block/CU, co-resident by construction.
__global__ __launch_bounds__(BLOCK) void k_fused(const float* __restrict__ x,
                                                 float* __restrict__ ws,
                                                 float* __restrict__ out) {
    __shared__ __align__(16) float s_tile[RIR_LEN];  // 96 KB private partial RIR
    __shared__ float4 s_e[CAPS];  // {amp, frac, amp*sin(pi*frac)/pi, i0}
    __shared__ int s_cnt;

    const float PIF = 3.14159265358979323846f;
    const int b = blockIdx.x >> 4;          // / NSL
    const int sl = blockIdx.x & (NSL - 1);
    const int tid = threadIdx.x;

    const float* xb = x + b * 9;
    const float r0 = xb[0] * 10.0f, r1 = xb[1] * 10.0f, r2 = xb[2] * 10.0f;
    const float m0 = xb[3] * r0, m1 = xb[4] * r1, m2 = xb[5] * r2;
    const float s0 = xb[6] * r0, s1 = xb[7] * r1, s2 = xb[8] * r2;

    if (tid == 0) s_cnt = 0;
    for (int j = tid * 4; j < RIR_LEN; j += BLOCK * 4)
        *(float4*)&s_tile[j] = make_float4(0.f, 0.f, 0.f, 0.f);
    __syncthreads();

    // ---- phase A: register-only scan of residue class (one candidate/thread)
    {
        int r = sl + tid * NSL;
        if (r < NTRIP) {
            int mi = r / (NM * NM);
            int rem = r - mi * (NM * NM);
            int mj = rem / NM;
            int mk = rem - mj * NM;

            float si, oi_; int qi; axis_entry(mi, si, oi_, qi);
            float sj, oj_; int qj; axis_entry(mj, sj, oj_, qj);
            float sk, ok_; int qk; axis_entry(mk, sk, ok_, qk);
            int q = qi + qj + qk;
            if (q <= 10) {
                float dx = si * s0 + oi_ * r0 - m0;
                float dy = sj * s1 + oj_ * r1 - m1;
                float dz = sk * s2 + ok_ * r2 - m2;
                float dist = sqrtf(dx * dx + dy * dy + dz * dz);

                float tau = SRf * dist / CSOUND;
                float i0f = floorf(tau);
                int i0 = (int)i0f;
                if (i0 + HALFT + 1 < RIR_LEN) {  // at least one in-range tap
                    float fr = tau - i0f;
                    float amp = c_beta[q] / (4.0f * PIF * dist);
                    int slot = atomicAdd(&s_cnt, 1);
                    float4 e;
                    e.x = amp;
                    e.y = fr;
                    e.z = amp * __sinf(PIF * fr) * (1.0f / PIF);
                    e.w = __int_as_float(i0);
                    s_e[slot] = e;
                }
            }
        }
    }
    __syncthreads();

    // ---- phase B: flattened (image, tap) paint; tap ki=0 contributes exactly 0
    const int n = s_cnt;
    const int total = n * (TAPS - 1);
    for (int w = tid; w < total; w += BLOCK) {
        int img = w / (TAPS - 1);
        int ki = w - img * (TAPS - 1) + 1;  // 1..80
        float4 e = s_e[img];
        int idx = __float_as_int(e.w) + HALFT + ki;
        if (idx >= RIR_LEN) continue;

        float tt = (float)(ki - HALFT) - e.y;  // in (-40, 40]
        float win = 0.5f * (1.0f + __cosf(PIF * (1.0f / 41.0f) * tt));
        float v = ((ki & 1) ? e.z : -e.z) * __builtin_amdgcn_rcpf(tt);
        v = (tt == 0.0f) ? e.x : v;  // exact-integer delay
        atomicAdd(&s_tile[idx], v * win);
    }
    __syncthreads();

    // ---- phase C: stream partial RIR to workspace (coalesced float4)
    float* wb = ws + (size_t)(b * NSL + sl) * RIR_LEN;
    for (int j = tid * 4; j < RIR_LEN; j += BLOCK * 4)
        *(float4*)&wb[j] = *(const float4*)&s_tile[j];

    // ---- grid-wide barrier (device-scope fence included)
    cg::this_grid().sync();

    // ---- phase D: reduce. Block (b,sl) owns samples [sl*SPAN, (sl+1)*SPAN).
    {
        int j4 = sl * SPAN + tid * 4;
        if (tid * 4 < SPAN) {
            const float* base = ws + (size_t)b * NSL * RIR_LEN + j4;
            float4 acc = *(const float4*)base;
            #pragma unroll
            for (int s = 1; s < NSL; ++s) {
                float4 v = *(const float4*)(base + (size_t)s * RIR_LEN);
                acc.x += v.x; acc.y += v.y; acc.z += v.z; acc.w += v.w;
            }
            *(float4*)(out + (size_t)b * RIR_LEN + j4) = acc;
        }
        if (blockIdx.x == 0 && tid < NB) {  // origins
            const float* xo = x + tid * 9;
            float q0 = xo[0] * 10.0f, q1 = xo[1] * 10.0f, q2 = xo[2] * 10.0f;
            float d0 = (xo[3] - xo[6]) * q0;
            float d1 = (xo[4] - xo[7]) * q1;
            float d2 = (xo[5] - xo[8]) * q2;
            float dist = sqrtf(d0 * d0 + d1 * d1 + d2 * d2);
            out[NB * RIR_LEN + tid] = 40.0f + SRf * dist / CSOUND;
        }
    }
}

extern "C" void kernel_launch(void* const* d_in, const int* in_sizes, int n_in,
                              void* d_out, int out_size, void* d_ws, size_t ws_size,
                              hipStream_t stream) {
    const float* x = (const float*)d_in[0];
    float* out = (float*)d_out;
    float* ws = (float*)d_ws;  // NB*NSL*RIR_LEN floats = 12.3 MB

    void* args[] = {(void*)&x, (void*)&ws, (void*)&out};
    hipLaunchCooperativeKernel((void*)k_fused, dim3(NB * NSL), dim3(BLOCK),
                               args, 0, stream);
}

// Round 12
// 29.864 us; speedup vs baseline: 1.8874x; 1.8874x over previous
//
#include <hip/hip_runtime.h>
#include <math.h>

#define SRf 48000.0f
#define CSOUND 343.0f
#define RIR_LEN 24000
#define TAPS 81
#define HALFT 40
#define NB 8
#define NM 21                 // per-axis entries with order <= 10
#define NTRIP (NM * NM * NM)  // 9261 candidate triples
#define NSL 16                // image-slices per batch -> 128 balanced paint blocks
#define BLOCK 1024
#define CAPS 256              // per-slice keeper capacity (max residue-class ~120)

// 0.9^q for q = 0..10
__device__ __constant__ float c_beta[11] = {
    1.0f, 0.9f, 0.81f, 0.729f, 0.6561f, 0.59049f, 0.531441f,
    0.4782969f, 0.43046721f, 0.387420489f, 0.3486784401f};

// Per-axis image table restricted to order <= 10 (pure arithmetic):
//   m in [0,10]:  p=0, n=m-5  -> sign=+1, off=2n, order=2|n|
//   m in [11,20]: p=1, n=m-15 -> sign=-1, off=2n, order=|n-1|+|n|
__device__ __forceinline__ void axis_entry(int m, float& sgn, float& off, int& ord) {
    if (m < 11) {
        int n = m - 5;
        sgn = 1.0f;
        off = 2.0f * (float)n;
        ord = 2 * abs(n);
    } else {
        int n = m - 15;
        sgn = -1.0f;
        off = 2.0f * (float)n;
        ord = abs(n - 1) + abs(n);
    }
}

// kernel 1: block = (batch, slice). Scan residue class register-only, track the
// nonzero window [lo,hi) via LDS atomicMin/Max, then zero/paint/write ONLY the
// window. Publishes the window to a header so the reduce can skip it too.
__global__ __launch_bounds__(BLOCK) void k_paint(const float* __restrict__ x,
                                                 float* __restrict__ ws,
                                                 int2* __restrict__ hdr) {
    __shared__ __align__(16) float s_tile[RIR_LEN];  // 96 KB (window-used)
    __shared__ float4 s_e[CAPS];  // {amp, frac, amp*sin(pi*frac)/pi, i0}
    __shared__ int s_cnt, s_lo, s_hi;

    const float PIF = 3.14159265358979323846f;
    const int b = blockIdx.x >> 4;          // / NSL
    const int sl = blockIdx.x & (NSL - 1);
    const int tid = threadIdx.x;

    const float* xb = x + b * 9;
    const float r0 = xb[0] * 10.0f, r1 = xb[1] * 10.0f, r2 = xb[2] * 10.0f;
    const float m0 = xb[3] * r0, m1 = xb[4] * r1, m2 = xb[5] * r2;
    const float s0 = xb[6] * r0, s1 = xb[7] * r1, s2 = xb[8] * r2;

    if (tid == 0) { s_cnt = 0; s_lo = RIR_LEN; s_hi = 0; }
    __syncthreads();

    // ---- phase A: register-only scan of residue class (one candidate/thread)
    {
        int r = sl + tid * NSL;
        if (r < NTRIP) {
            int mi = r / (NM * NM);
            int rem = r - mi * (NM * NM);
            int mj = rem / NM;
            int mk = rem - mj * NM;

            float si, oi_; int qi; axis_entry(mi, si, oi_, qi);
            float sj, oj_; int qj; axis_entry(mj, sj, oj_, qj);
            float sk, ok_; int qk; axis_entry(mk, sk, ok_, qk);
            int q = qi + qj + qk;
            if (q <= 10) {
                float dx = si * s0 + oi_ * r0 - m0;
                float dy = sj * s1 + oj_ * r1 - m1;
                float dz = sk * s2 + ok_ * r2 - m2;
                float dist = sqrtf(dx * dx + dy * dy + dz * dz);

                float tau = SRf * dist / CSOUND;
                float i0f = floorf(tau);
                int i0 = (int)i0f;
                if (i0 + HALFT + 1 < RIR_LEN) {  // at least one in-range tap
                    float fr = tau - i0f;
                    float amp = c_beta[q] / (4.0f * PIF * dist);
                    int slot = atomicAdd(&s_cnt, 1);
                    float4 e;
                    e.x = amp;
                    e.y = fr;
                    e.z = amp * __sinf(PIF * fr) * (1.0f / PIF);
                    e.w = __int_as_float(i0);
                    s_e[slot] = e;
                    atomicMin(&s_lo, i0 + HALFT + 1);                 // first tap idx
                    atomicMax(&s_hi, min(i0 + HALFT + TAPS, RIR_LEN));  // excl end
                }
            }
        }
    }
    __syncthreads();

    const int lo4 = s_lo & ~3;
    const int hi4 = (s_hi + 3) & ~3;  // <= RIR_LEN (RIR_LEN % 4 == 0)
    if (tid == 0) hdr[blockIdx.x] = make_int2(lo4, hi4);

    if (lo4 < hi4) {
        // ---- zero only the window
        for (int j = lo4 + tid * 4; j < hi4; j += BLOCK * 4)
            *(float4*)&s_tile[j] = make_float4(0.f, 0.f, 0.f, 0.f);
        __syncthreads();

        // ---- phase B: flattened (image, tap) paint; tap ki=0 contributes 0
        const int n = s_cnt;
        const int total = n * (TAPS - 1);
        for (int w = tid; w < total; w += BLOCK) {
            int img = w / (TAPS - 1);
            int ki = w - img * (TAPS - 1) + 1;  // 1..80
            float4 e = s_e[img];
            int idx = __float_as_int(e.w) + HALFT + ki;
            if (idx >= RIR_LEN) continue;

            float tt = (float)(ki - HALFT) - e.y;  // in (-40, 40]
            float win = 0.5f * (1.0f + __cosf(PIF * (1.0f / 41.0f) * tt));
            float v = ((ki & 1) ? e.z : -e.z) * __builtin_amdgcn_rcpf(tt);
            v = (tt == 0.0f) ? e.x : v;  // exact-integer delay
            atomicAdd(&s_tile[idx], v * win);
        }
        __syncthreads();

        // ---- phase C: stream only the window to workspace (coalesced float4)
        float* wb = ws + (size_t)blockIdx.x * RIR_LEN;
        for (int j = lo4 + tid * 4; j < hi4; j += BLOCK * 4)
            *(float4*)&wb[j] = *(const float4*)&s_tile[j];
    }
}

// kernel 2: windowed sum of the NSL partials per batch -> out; plus origins.
__global__ __launch_bounds__(256) void k_reduce(const float* __restrict__ x,
                                                const float* __restrict__ ws,
                                                const int2* __restrict__ hdr,
                                                float* __restrict__ out) {
    int t4 = (blockIdx.x * 256 + threadIdx.x) * 4;
    if (t4 < NB * RIR_LEN) {
        int b = t4 / RIR_LEN;
        int j = t4 - b * RIR_LEN;
        const float* base = ws + (size_t)b * NSL * RIR_LEN + j;
        float4 acc = make_float4(0.f, 0.f, 0.f, 0.f);
        #pragma unroll
        for (int s = 0; s < NSL; ++s) {
            int2 w = hdr[b * NSL + s];
            if (j >= w.x && j < w.y) {
                float4 v = *(const float4*)(base + (size_t)s * RIR_LEN);
                acc.x += v.x; acc.y += v.y; acc.z += v.z; acc.w += v.w;
            }
        }
        *(float4*)(out + t4) = acc;
    }
    if (blockIdx.x == 0 && threadIdx.x < NB) {
        const float* xb = x + threadIdx.x * 9;
        float r0 = xb[0] * 10.0f, r1 = xb[1] * 10.0f, r2 = xb[2] * 10.0f;
        float d0 = (xb[3] - xb[6]) * r0;
        float d1 = (xb[4] - xb[7]) * r1;
        float d2 = (xb[5] - xb[8]) * r2;
        float dist = sqrtf(d0 * d0 + d1 * d1 + d2 * d2);
        out[NB * RIR_LEN + threadIdx.x] = 40.0f + SRf * dist / CSOUND;
    }
}

extern "C" void kernel_launch(void* const* d_in, const int* in_sizes, int n_in,
                              void* d_out, int out_size, void* d_ws, size_t ws_size,
                              hipStream_t stream) {
    const float* x = (const float*)d_in[0];
    float* out = (float*)d_out;
    float* ws = (float*)d_ws;  // partials: NB*NSL*RIR_LEN floats = 12.3 MB
    int2* hdr = (int2*)((char*)d_ws + (size_t)NB * NSL * RIR_LEN * sizeof(float));

    k_paint<<<NB * NSL, BLOCK, 0, stream>>>(x, ws, hdr);
    int rblocks = (NB * RIR_LEN / 4 + 255) / 256;  // 188
    k_reduce<<<rblocks, 256, 0, stream>>>(x, ws, hdr, out);
}